// Round 1
// baseline (3058.699 us; speedup 1.0000x reference)
//
#include <hip/hip_runtime.h>

// Problem constants (also derived from in_sizes at launch for robustness)
// N=50000 nodes, E=500000 edges, D=128, R=8, L=2
constexpr int D = 128;
constexpr int R = 8;
constexpr int KTOT = R * D + D;   // 1152: [M | h] concatenated K dimension
constexpr float BN_EPS = 1e-5f;

// ---------------------------------------------------------------------------
// Scatter: per edge, m = relu(h[src] + xe[e]); atomicAdd into M[dst, r*128+c]
// 32 lanes per edge, float4 per lane. lane 0 counts.
// ---------------------------------------------------------------------------
__global__ __launch_bounds__(256) void scatter_k(
    const float* __restrict__ h,    // [N,128]
    const float* __restrict__ xe,   // [E,128]
    const int*   __restrict__ ei,   // [2,E]
    const int*   __restrict__ et,   // [E]
    float* __restrict__ M,          // [N, 1024]
    float* __restrict__ cnt,        // [N, 8]
    int E) {
  int g = blockIdx.x * 256 + threadIdx.x;
  int e = g >> 5;
  int lane = g & 31;
  if (e >= E) return;
  int src = ei[e];
  int dst = ei[E + e];
  int r = et[e];
  float4 xv = ((const float4*)xe)[e * 32 + lane];
  float4 hv = ((const float4*)h)[src * 32 + lane];
  float4 m;
  m.x = fmaxf(xv.x + hv.x, 0.f);
  m.y = fmaxf(xv.y + hv.y, 0.f);
  m.z = fmaxf(xv.z + hv.z, 0.f);
  m.w = fmaxf(xv.w + hv.w, 0.f);
  float* p = M + (size_t)dst * 1024 + r * 128 + lane * 4;
  atomicAdd(p + 0, m.x);
  atomicAdd(p + 1, m.y);
  atomicAdd(p + 2, m.z);
  atomicAdd(p + 3, m.w);
  if (lane == 0) atomicAdd(cnt + dst * 8 + r, 1.0f);
}

// ---------------------------------------------------------------------------
// GEMM: out[n,o] = sum_k A[n,k] * Wcat[k,o] + bias[o]
//   A[n,k] = k<1024 ? M[n,k] * (1/max(cnt[n][k>>7],1)) : h[n,k-1024]
//   Wcat[k,o] = k<1024 ? weight[k*128+o] : root[(k-1024)*128+o]
// BM=64 rows/block, 256 threads, BK=32. Fused BN column sum/sumsq epilogue.
// ---------------------------------------------------------------------------
__global__ __launch_bounds__(256) void gemm_k(
    const float* __restrict__ M,      // [N,1024]
    const float* __restrict__ cnt,    // [N,8]
    const float* __restrict__ h,      // [N,128]
    const float* __restrict__ W,      // [1024,128] (weight[l] flattened)
    const float* __restrict__ root,   // [128,128]
    const float* __restrict__ bias,   // [128]
    float* __restrict__ out,          // [N,128]
    float* __restrict__ colstats,     // [256]: [0:128) sum, [128:256) sumsq
    int N) {
  __shared__ float As[64][33];   // +1 pad: conflict-free column reads
  __shared__ float Bs[32][128];
  __shared__ float redS[128];
  __shared__ float redQ[128];

  const int tid = threadIdx.x;
  const int tx = tid & 31;        // column quad: cols 4*tx..4*tx+3
  const int ty = tid >> 5;        // row group: rows ty, ty+8, ..., ty+56
  const int n0 = blockIdx.x * 64;

  float acc[8][4];
  #pragma unroll
  for (int i = 0; i < 8; ++i)
    #pragma unroll
    for (int j = 0; j < 4; ++j) acc[i][j] = 0.f;

  for (int k0 = 0; k0 < KTOT; k0 += 32) {
    // --- stage A [64][32]: 2 halves, each thread one float4 ---
    #pragma unroll
    for (int half = 0; half < 2; ++half) {
      int row = half * 32 + (tid >> 3);
      int kq  = (tid & 7) * 4;
      int n   = n0 + row;
      float4 a = make_float4(0.f, 0.f, 0.f, 0.f);
      if (n < N) {
        if (k0 < 1024) {
          a = *(const float4*)(M + (size_t)n * 1024 + k0 + kq);
          float c = cnt[n * 8 + (k0 >> 7)];
          float ic = 1.0f / fmaxf(c, 1.0f);
          a.x *= ic; a.y *= ic; a.z *= ic; a.w *= ic;
        } else {
          a = *(const float4*)(h + (size_t)n * 128 + (k0 - 1024) + kq);
        }
      }
      As[row][kq + 0] = a.x;
      As[row][kq + 1] = a.y;
      As[row][kq + 2] = a.z;
      As[row][kq + 3] = a.w;
    }
    // --- stage B [32][128]: 4 passes, one float4 each ---
    #pragma unroll
    for (int pass = 0; pass < 4; ++pass) {
      int kk = pass * 8 + (tid >> 5);
      int col = tx * 4;
      int kg = k0 + kk;
      const float* sp = (kg < 1024) ? (W + (size_t)kg * 128 + col)
                                    : (root + (size_t)(kg - 1024) * 128 + col);
      *(float4*)&Bs[kk][col] = *(const float4*)sp;
    }
    __syncthreads();
    #pragma unroll
    for (int kk = 0; kk < 32; ++kk) {
      float4 b4 = *(const float4*)&Bs[kk][tx * 4];
      #pragma unroll
      for (int i = 0; i < 8; ++i) {
        float a = As[ty + 8 * i][kk];
        acc[i][0] = fmaf(a, b4.x, acc[i][0]);
        acc[i][1] = fmaf(a, b4.y, acc[i][1]);
        acc[i][2] = fmaf(a, b4.z, acc[i][2]);
        acc[i][3] = fmaf(a, b4.w, acc[i][3]);
      }
    }
    __syncthreads();
  }

  // --- epilogue: bias add, store, fused BN column stats ---
  float b0 = bias[tx * 4 + 0], b1 = bias[tx * 4 + 1];
  float b2 = bias[tx * 4 + 2], b3 = bias[tx * 4 + 3];
  if (tid < 128) { redS[tid] = 0.f; redQ[tid] = 0.f; }
  __syncthreads();

  float ps[4] = {0.f, 0.f, 0.f, 0.f};
  float pq[4] = {0.f, 0.f, 0.f, 0.f};
  #pragma unroll
  for (int i = 0; i < 8; ++i) {
    int n = n0 + ty + 8 * i;
    if (n < N) {
      float4 o;
      o.x = acc[i][0] + b0;
      o.y = acc[i][1] + b1;
      o.z = acc[i][2] + b2;
      o.w = acc[i][3] + b3;
      *(float4*)(out + (size_t)n * 128 + tx * 4) = o;
      ps[0] += o.x; pq[0] += o.x * o.x;
      ps[1] += o.y; pq[1] += o.y * o.y;
      ps[2] += o.z; pq[2] += o.z * o.z;
      ps[3] += o.w; pq[3] += o.w * o.w;
    }
  }
  #pragma unroll
  for (int j = 0; j < 4; ++j) {
    atomicAdd(&redS[tx * 4 + j], ps[j]);
    atomicAdd(&redQ[tx * 4 + j], pq[j]);
  }
  __syncthreads();
  if (tid < 128) {
    atomicAdd(&colstats[tid], redS[tid]);
    atomicAdd(&colstats[128 + tid], redQ[tid]);
  }
}

// ---------------------------------------------------------------------------
// BN apply (in-place capable): out = (x-mu)*rsqrt(var+eps)*gamma + beta [+relu]
// ---------------------------------------------------------------------------
__global__ __launch_bounds__(256) void bn_apply_k(
    const float* __restrict__ in, float* __restrict__ out,
    const float* __restrict__ colstats,
    const float* __restrict__ gamma, const float* __restrict__ beta,
    int N, int doRelu) {
  int g = blockIdx.x * 256 + threadIdx.x;   // one float4 each
  if (g >= N * 32) return;
  int c0 = (g & 31) * 4;
  float invN = 1.0f / (float)N;
  float4 v = ((const float4*)in)[g];
  float4 o;
  #pragma unroll
  for (int j = 0; j < 4; ++j) {
    int c = c0 + j;
    float mu = colstats[c] * invN;
    float var = colstats[128 + c] * invN - mu * mu;
    float scale = rsqrtf(var + BN_EPS) * gamma[c];
    float shift = beta[c] - mu * scale;
    float x = (j == 0) ? v.x : (j == 1) ? v.y : (j == 2) ? v.z : v.w;
    float y = x * scale + shift;
    if (doRelu) y = fmaxf(y, 0.f);
    if (j == 0) o.x = y; else if (j == 1) o.y = y; else if (j == 2) o.z = y; else o.w = y;
  }
  ((float4*)out)[g] = o;
}

extern "C" void kernel_launch(void* const* d_in, const int* in_sizes, int n_in,
                              void* d_out, int out_size, void* d_ws, size_t ws_size,
                              hipStream_t stream) {
  const float* x      = (const float*)d_in[0];   // [N,128]
  const float* xe     = (const float*)d_in[1];   // [E,128]
  const int*   ei     = (const int*)d_in[2];     // [2,E]
  const int*   et     = (const int*)d_in[3];     // [E]
  const float* weight = (const float*)d_in[4];   // [2,8,128,128]
  const float* root   = (const float*)d_in[5];   // [2,128,128]
  const float* bias   = (const float*)d_in[6];   // [2,128]
  const float* gamma  = (const float*)d_in[7];   // [2,128]
  const float* beta   = (const float*)d_in[8];   // [2,128]
  float* out = (float*)d_out;

  const int N = in_sizes[0] / D;   // 50000
  const int E = in_sizes[3];       // 500000

  // workspace layout (floats)
  float* M        = (float*)d_ws;                    // N*1024
  float* cnt      = M + (size_t)N * 1024;            // N*8 (contiguous with M)
  float* h1       = cnt + (size_t)N * 8;             // N*128
  float* colstats = h1 + (size_t)N * 128;            // 256

  const int scatterBlocks = (E * 32 + 255) / 256;
  const int gemmBlocks    = (N + 63) / 64;
  const int bnBlocks      = (N * 32 + 255) / 256;

  for (int l = 0; l < 2; ++l) {
    const float* hin = (l == 0) ? x : h1;
    float* opre      = (l == 0) ? h1 : out;

    hipMemsetAsync(M, 0, (size_t)(N * 1024 + N * 8) * sizeof(float), stream);
    scatter_k<<<scatterBlocks, 256, 0, stream>>>(hin, xe, ei, et, M, cnt, E);

    hipMemsetAsync(colstats, 0, 256 * sizeof(float), stream);
    gemm_k<<<gemmBlocks, 256, 0, stream>>>(
        M, cnt, hin,
        weight + (size_t)l * R * D * D,
        root + (size_t)l * D * D,
        bias + (size_t)l * D,
        opre, colstats, N);

    bn_apply_k<<<bnBlocks, 256, 0, stream>>>(
        opre, opre, colstats, gamma + (size_t)l * D, beta + (size_t)l * D,
        N, (l == 0) ? 1 : 0);
  }
}

// Round 2
// 865.917 us; speedup vs baseline: 3.5323x; 3.5323x over previous
//
#include <hip/hip_runtime.h>
#include <hip/hip_bf16.h>

typedef __attribute__((ext_vector_type(8))) short bf16x8;
typedef __attribute__((ext_vector_type(4))) float f32x4;

constexpr int D = 128;
constexpr int R = 8;
constexpr float BN_EPS = 1e-5f;

__device__ __forceinline__ unsigned short f2bf(float x) {
  __hip_bfloat16 b = __float2bfloat16(x);
  union { __hip_bfloat16 b; unsigned short u; } c; c.b = b; return c.u;
}

// ---------------------------------------------------------------------------
// Counting sort of edges by key = dst*8 + rel  (structure shared by both layers)
// ---------------------------------------------------------------------------
__global__ __launch_bounds__(256) void hist_k(const int* __restrict__ ei,
                                              const int* __restrict__ et,
                                              int* __restrict__ cnt, int E) {
  int e = blockIdx.x * 256 + threadIdx.x;
  if (e >= E) return;
  atomicAdd(&cnt[ei[E + e] * 8 + et[e]], 1);
}

// per-block (4096 elems) exclusive scan; writes partial prefix + block sums
__global__ __launch_bounds__(256) void scan_partial_k(const int* __restrict__ cnt,
                                                      int* __restrict__ offs,
                                                      int* __restrict__ bsum, int NK) {
  __shared__ int s[256];
  int tid = threadIdx.x;
  int base = blockIdx.x * 4096 + tid * 16;
  int loc[16];
  int sum = 0;
  #pragma unroll
  for (int i = 0; i < 16; ++i) {
    int idx = base + i;
    int v = (idx < NK) ? cnt[idx] : 0;
    loc[i] = sum; sum += v;
  }
  s[tid] = sum;
  __syncthreads();
  if (tid == 0) {
    int run = 0;
    for (int i = 0; i < 256; ++i) { int t = s[i]; s[i] = run; run += t; }
    bsum[blockIdx.x] = run;
  }
  __syncthreads();
  int off = s[tid];
  #pragma unroll
  for (int i = 0; i < 16; ++i) {
    int idx = base + i;
    if (idx < NK) offs[idx] = off + loc[i];
  }
}

__global__ void scan_bsums_k(int* __restrict__ bsum, int nb) {
  if (threadIdx.x == 0 && blockIdx.x == 0) {
    int run = 0;
    for (int b = 0; b < nb; ++b) { int t = bsum[b]; bsum[b] = run; run += t; }
  }
}

__global__ __launch_bounds__(256) void scan_addback_k(int* __restrict__ offs,
                                                      const int* __restrict__ bsum,
                                                      int NK, int E) {
  int idx = blockIdx.x * 256 + threadIdx.x;
  if (idx < NK) offs[idx] += bsum[idx >> 12];
  if (idx == 0) offs[NK] = E;
}

__global__ __launch_bounds__(256) void place_k(const int* __restrict__ ei,
                                               const int* __restrict__ et,
                                               const int* __restrict__ offs,
                                               int* __restrict__ cnt,
                                               int* __restrict__ perm, int E) {
  int e = blockIdx.x * 256 + threadIdx.x;
  if (e >= E) return;
  int key = ei[E + e] * 8 + et[e];
  int pos = offs[key] + atomicAdd(&cnt[key], 1);
  perm[pos] = e;
}

// ---------------------------------------------------------------------------
// Segment mean aggregation: one 64-lane wave per (dst,rel) segment.
// lanes 0-31 handle even edges, 32-63 odd; combine via shfl_xor(32).
// Output: Mb [NK][128] bf16, k-swizzled per 32-channel tile for MFMA frags.
// swizzled pos within tile for channel kk: 8*((kk&15)>>2) + 4*(kk>>4) + (kk&3)
// ---------------------------------------------------------------------------
__global__ __launch_bounds__(256) void agg_k(const float* __restrict__ h,
                                             const float* __restrict__ xe,
                                             const int* __restrict__ ei,
                                             const int* __restrict__ perm,
                                             const int* __restrict__ offs,
                                             unsigned short* __restrict__ Mb, int NK) {
  int wv = threadIdx.x >> 6;
  int seg = blockIdx.x * 4 + wv;
  if (seg >= NK) return;
  int lane = threadIdx.x & 63;
  int half = lane >> 5, c = lane & 31;
  int start = offs[seg], end = offs[seg + 1];
  float4 acc = make_float4(0.f, 0.f, 0.f, 0.f);
  for (int i = start + half; i < end; i += 2) {
    int e = perm[i];
    int src = ei[e];
    float4 xv = ((const float4*)xe)[(size_t)e * 32 + c];
    float4 hv = ((const float4*)h)[(size_t)src * 32 + c];
    acc.x += fmaxf(xv.x + hv.x, 0.f);
    acc.y += fmaxf(xv.y + hv.y, 0.f);
    acc.z += fmaxf(xv.z + hv.z, 0.f);
    acc.w += fmaxf(xv.w + hv.w, 0.f);
  }
  acc.x += __shfl_xor(acc.x, 32);
  acc.y += __shfl_xor(acc.y, 32);
  acc.z += __shfl_xor(acc.z, 32);
  acc.w += __shfl_xor(acc.w, 32);
  if (half == 0) {
    int len = end - start;
    float inv = (len > 0) ? 1.0f / (float)len : 0.f;
    int pos = (c >> 3) * 32 + (c & 3) * 8 + ((c >> 2) & 1) * 4;
    ushort4 u;
    u.x = f2bf(acc.x * inv); u.y = f2bf(acc.y * inv);
    u.z = f2bf(acc.z * inv); u.w = f2bf(acc.w * inv);
    *(ushort4*)(Mb + (size_t)seg * 128 + pos) = u;
  }
}

// cast fp32 [N,128] -> bf16 swizzled [N,128]
__global__ __launch_bounds__(256) void cast_swz_k(const float* __restrict__ in,
                                                  unsigned short* __restrict__ outb, int n4) {
  int gi = blockIdx.x * 256 + threadIdx.x;
  if (gi >= n4) return;
  int n = gi >> 5, c = gi & 31;
  float4 v = ((const float4*)in)[gi];
  int pos = (c >> 3) * 32 + (c & 3) * 8 + ((c >> 2) & 1) * 4;
  ushort4 u;
  u.x = f2bf(v.x); u.y = f2bf(v.y); u.z = f2bf(v.z); u.w = f2bf(v.w);
  *(ushort4*)(outb + (size_t)n * 128 + pos) = u;
}

// W[1152,128] (weight_l | root_l) -> transposed, k-swizzled, split hi/lo bf16
__global__ __launch_bounds__(256) void wcast_k(const float* __restrict__ W,
                                               const float* __restrict__ root,
                                               unsigned short* __restrict__ Whi,
                                               unsigned short* __restrict__ Wlo) {
  int idx = blockIdx.x * 256 + threadIdx.x;   // 1152*128 = 147456
  if (idx >= 1152 * 128) return;
  int k = idx >> 7, col = idx & 127;
  float w = (k < 1024) ? W[idx] : root[idx - 1024 * 128];
  __hip_bfloat16 hb = __float2bfloat16(w);
  float hif = __bfloat162float(hb);
  int kk = k & 31;
  int pos = (k & ~31) + ((kk & 15) >> 2) * 8 + (kk >> 4) * 4 + (kk & 3);
  union { __hip_bfloat16 b; unsigned short u; } ch; ch.b = hb;
  Whi[col * 1152 + pos] = ch.u;
  Wlo[col * 1152 + pos] = f2bf(w - hif);
}

// ---------------------------------------------------------------------------
// MFMA GEMM: out[n,o] = sum_k A[n,k] * (Whi+Wlo)[k,o] + bias[o]
// A = [Mb | hb] bf16 swizzled, loaded as fragments straight from global.
// 128 thr = 2 waves, each wave: 32 rows x 128 cols (2x8 fragments of 16x16).
// Fused BN column sum/sumsq epilogue.
// ---------------------------------------------------------------------------
__global__ __launch_bounds__(128) void gemm_k(
    const unsigned short* __restrict__ Mb,   // [N,1024] swz
    const unsigned short* __restrict__ hb,   // [N,128] swz
    const unsigned short* __restrict__ Whi,  // [128,1152] swz-k
    const unsigned short* __restrict__ Wlo,
    const float* __restrict__ bias,
    float* __restrict__ out,
    float* __restrict__ colstats, int N) {
  __shared__ float ldsS[128], ldsQ[128];
  int tid = threadIdx.x;
  int wv = tid >> 6, lane = tid & 63;
  int lr = lane & 15, g = lane >> 4;
  int r0 = blockIdx.x * 64 + wv * 32;
  int row0 = min(r0 + lr, N - 1);
  int row1 = min(r0 + 16 + lr, N - 1);
  const unsigned short* pbh = Whi + lr * 1152 + g * 8;
  const unsigned short* pbl = Wlo + lr * 1152 + g * 8;

  f32x4 acc[2][8];
  #pragma unroll
  for (int a = 0; a < 2; ++a)
    #pragma unroll
    for (int b = 0; b < 8; ++b) acc[a][b] = (f32x4){0.f, 0.f, 0.f, 0.f};

  ldsS[tid] = 0.f; ldsQ[tid] = 0.f;   // block is exactly 128 threads

  for (int t = 0; t < 36; ++t) {
    const unsigned short *pa0, *pa1;
    if (t < 32) {
      int o = t * 32 + g * 8;
      pa0 = Mb + (size_t)row0 * 1024 + o;
      pa1 = Mb + (size_t)row1 * 1024 + o;
    } else {
      int o = (t - 32) * 32 + g * 8;
      pa0 = hb + (size_t)row0 * 128 + o;
      pa1 = hb + (size_t)row1 * 128 + o;
    }
    bf16x8 a0 = *(const bf16x8*)pa0;
    bf16x8 a1 = *(const bf16x8*)pa1;
    #pragma unroll
    for (int cf = 0; cf < 8; ++cf) {
      bf16x8 bh = *(const bf16x8*)(pbh + cf * 18432 + t * 32);
      bf16x8 bl = *(const bf16x8*)(pbl + cf * 18432 + t * 32);
      acc[0][cf] = __builtin_amdgcn_mfma_f32_16x16x32_bf16(a0, bh, acc[0][cf], 0, 0, 0);
      acc[0][cf] = __builtin_amdgcn_mfma_f32_16x16x32_bf16(a0, bl, acc[0][cf], 0, 0, 0);
      acc[1][cf] = __builtin_amdgcn_mfma_f32_16x16x32_bf16(a1, bh, acc[1][cf], 0, 0, 0);
      acc[1][cf] = __builtin_amdgcn_mfma_f32_16x16x32_bf16(a1, bl, acc[1][cf], 0, 0, 0);
    }
  }
  __syncthreads();   // covers ldsS/ldsQ init too

  #pragma unroll
  for (int cf = 0; cf < 8; ++cf) {
    int col = cf * 16 + lr;
    float bs = bias[col];
    float s = 0.f, q = 0.f;
    #pragma unroll
    for (int rf = 0; rf < 2; ++rf) {
      #pragma unroll
      for (int j = 0; j < 4; ++j) {
        int row = r0 + rf * 16 + g * 4 + j;
        if (row < N) {
          float v = acc[rf][cf][j] + bs;
          out[(size_t)row * 128 + col] = v;
          s += v; q += v * v;
        }
      }
    }
    s += __shfl_xor(s, 16); s += __shfl_xor(s, 32);
    q += __shfl_xor(q, 16); q += __shfl_xor(q, 32);
    if (g == 0) { atomicAdd(&ldsS[col], s); atomicAdd(&ldsQ[col], q); }
  }
  __syncthreads();
  if (tid < 128) {
    atomicAdd(&colstats[tid], ldsS[tid]);
    atomicAdd(&colstats[128 + tid], ldsQ[tid]);
  }
}

// ---------------------------------------------------------------------------
// BN apply; optionally also emit bf16-swizzled copy for next layer's root term
// ---------------------------------------------------------------------------
__global__ __launch_bounds__(256) void bn_apply_k(
    const float* __restrict__ in, float* __restrict__ out,
    unsigned short* __restrict__ hbOut,
    const float* __restrict__ colstats,
    const float* __restrict__ gamma, const float* __restrict__ beta,
    int N, int doRelu) {
  int gi = blockIdx.x * 256 + threadIdx.x;
  if (gi >= N * 32) return;
  int n = gi >> 5, c = gi & 31;
  int c0 = c * 4;
  float invN = 1.0f / (float)N;
  float4 v = ((const float4*)in)[gi];
  float4 o;
  #pragma unroll
  for (int j = 0; j < 4; ++j) {
    int cc = c0 + j;
    float mu = colstats[cc] * invN;
    float var = colstats[128 + cc] * invN - mu * mu;
    float scale = rsqrtf(var + BN_EPS) * gamma[cc];
    float shift = beta[cc] - mu * scale;
    float x = (j == 0) ? v.x : (j == 1) ? v.y : (j == 2) ? v.z : v.w;
    float y = x * scale + shift;
    if (doRelu) y = fmaxf(y, 0.f);
    if (j == 0) o.x = y; else if (j == 1) o.y = y; else if (j == 2) o.z = y; else o.w = y;
  }
  ((float4*)out)[gi] = o;
  if (hbOut) {
    int pos = (c >> 3) * 32 + (c & 3) * 8 + ((c >> 2) & 1) * 4;
    ushort4 u;
    u.x = f2bf(o.x); u.y = f2bf(o.y); u.z = f2bf(o.z); u.w = f2bf(o.w);
    *(ushort4*)(hbOut + (size_t)n * 128 + pos) = u;
  }
}

extern "C" void kernel_launch(void* const* d_in, const int* in_sizes, int n_in,
                              void* d_out, int out_size, void* d_ws, size_t ws_size,
                              hipStream_t stream) {
  const float* x      = (const float*)d_in[0];
  const float* xe     = (const float*)d_in[1];
  const int*   ei     = (const int*)d_in[2];
  const int*   et     = (const int*)d_in[3];
  const float* weight = (const float*)d_in[4];
  const float* root   = (const float*)d_in[5];
  const float* bias   = (const float*)d_in[6];
  const float* gamma  = (const float*)d_in[7];
  const float* beta   = (const float*)d_in[8];
  float* out = (float*)d_out;

  const int N = in_sizes[0] / D;   // 50000
  const int E = in_sizes[3];       // 500000
  const int NK = N * R;            // 400000

  // workspace layout (256B-aligned chunks)
  char* w = (char*)d_ws;
  size_t off = 0;
  auto alloc = [&](size_t bytes) { char* p = w + off; off = (off + bytes + 255) & ~(size_t)255; return p; };
  unsigned short* Mb   = (unsigned short*)alloc((size_t)NK * 128 * 2);
  unsigned short* hb   = (unsigned short*)alloc((size_t)N * 128 * 2);
  float*          h1   = (float*)alloc((size_t)N * 128 * 4);
  unsigned short* Whi  = (unsigned short*)alloc(1152 * 128 * 2);
  unsigned short* Wlo  = (unsigned short*)alloc(1152 * 128 * 2);
  int*            offs = (int*)alloc((size_t)(NK + 1) * 4);
  int*            cnt  = (int*)alloc((size_t)NK * 4);
  int*            perm = (int*)alloc((size_t)E * 4);
  int*            bsum = (int*)alloc(512 * 4);
  float*          cst  = (float*)alloc(256 * 4);

  const int NB = (NK + 4095) / 4096;

  // --- counting sort (edge structure; shared by both layers) ---
  hipMemsetAsync(cnt, 0, (size_t)NK * 4, stream);
  hist_k<<<(E + 255) / 256, 256, 0, stream>>>(ei, et, cnt, E);
  scan_partial_k<<<NB, 256, 0, stream>>>(cnt, offs, bsum, NK);
  scan_bsums_k<<<1, 64, 0, stream>>>(bsum, NB);
  scan_addback_k<<<(NK + 255) / 256, 256, 0, stream>>>(offs, bsum, NK, E);
  hipMemsetAsync(cnt, 0, (size_t)NK * 4, stream);
  place_k<<<(E + 255) / 256, 256, 0, stream>>>(ei, et, offs, cnt, perm, E);

  const int aggBlocks  = (NK + 3) / 4;
  const int gemmBlocks = (N + 63) / 64;
  const int castBlocks = (N * 32 + 255) / 256;

  for (int l = 0; l < 2; ++l) {
    const float* hin = (l == 0) ? x : h1;
    float* opre      = (l == 0) ? h1 : out;

    wcast_k<<<576, 256, 0, stream>>>(weight + (size_t)l * 1024 * 128,
                                     root + (size_t)l * 128 * 128, Whi, Wlo);
    agg_k<<<aggBlocks, 256, 0, stream>>>(hin, xe, ei, perm, offs, Mb, NK);
    if (l == 0)
      cast_swz_k<<<castBlocks, 256, 0, stream>>>(x, hb, N * 32);
    hipMemsetAsync(cst, 0, 256 * 4, stream);
    gemm_k<<<gemmBlocks, 128, 0, stream>>>(Mb, hb, Whi, Wlo,
                                           bias + (size_t)l * D, opre, cst, N);
    bn_apply_k<<<castBlocks, 256, 0, stream>>>(
        opre, opre, (l == 0) ? hb : (unsigned short*)nullptr,
        cst, gamma + (size_t)l * D, beta + (size_t)l * D, N, (l == 0) ? 1 : 0);
  }
}

// Round 3
// 646.783 us; speedup vs baseline: 4.7291x; 1.3388x over previous
//
#include <hip/hip_runtime.h>
#include <hip/hip_bf16.h>

typedef __attribute__((ext_vector_type(8))) short bf16x8;
typedef __attribute__((ext_vector_type(4))) float f32x4;

constexpr int D = 128;
constexpr int R = 8;
constexpr float BN_EPS = 1e-5f;

__device__ __forceinline__ unsigned short f2bf(float x) {
  __hip_bfloat16 b = __float2bfloat16(x);
  union { __hip_bfloat16 b; unsigned short u; } c; c.b = b; return c.u;
}

// ---------------------------------------------------------------------------
// Counting sort of edges by key = dst*8 + rel (structure shared by both layers)
// ---------------------------------------------------------------------------
__global__ __launch_bounds__(256) void hist_k(const int* __restrict__ ei,
                                              const int* __restrict__ et,
                                              int* __restrict__ cnt, int E) {
  int e = blockIdx.x * 256 + threadIdx.x;
  if (e >= E) return;
  atomicAdd(&cnt[ei[E + e] * 8 + et[e]], 1);
}

__global__ __launch_bounds__(256) void scan_partial_k(const int* __restrict__ cnt,
                                                      int* __restrict__ offs,
                                                      int* __restrict__ bsum, int NK) {
  __shared__ int s[256];
  int tid = threadIdx.x;
  int base = blockIdx.x * 4096 + tid * 16;
  int loc[16];
  int sum = 0;
  #pragma unroll
  for (int i = 0; i < 16; ++i) {
    int idx = base + i;
    int v = (idx < NK) ? cnt[idx] : 0;
    loc[i] = sum; sum += v;
  }
  s[tid] = sum;
  __syncthreads();
  if (tid == 0) {
    int run = 0;
    for (int i = 0; i < 256; ++i) { int t = s[i]; s[i] = run; run += t; }
    bsum[blockIdx.x] = run;
  }
  __syncthreads();
  int off = s[tid];
  #pragma unroll
  for (int i = 0; i < 16; ++i) {
    int idx = base + i;
    if (idx < NK) offs[idx] = off + loc[i];
  }
}

__global__ void scan_bsums_k(int* __restrict__ bsum, int nb) {
  if (threadIdx.x == 0 && blockIdx.x == 0) {
    int run = 0;
    for (int b = 0; b < nb; ++b) { int t = bsum[b]; bsum[b] = run; run += t; }
  }
}

__global__ __launch_bounds__(256) void scan_addback_k(int* __restrict__ offs,
                                                      const int* __restrict__ bsum,
                                                      int NK, int E) {
  int idx = blockIdx.x * 256 + threadIdx.x;
  if (idx < NK) offs[idx] += bsum[idx >> 12];
  if (idx == 0) offs[NK] = E;
}

__global__ __launch_bounds__(256) void place_k(const int* __restrict__ ei,
                                               const int* __restrict__ et,
                                               const int* __restrict__ offs,
                                               int* __restrict__ cnt,
                                               int* __restrict__ perm, int E) {
  int e = blockIdx.x * 256 + threadIdx.x;
  if (e >= E) return;
  int key = ei[E + e] * 8 + et[e];
  int pos = offs[key] + atomicAdd(&cnt[key], 1);
  perm[pos] = e;
}

// ---------------------------------------------------------------------------
// Segment mean aggregation: one 64-lane wave per (dst,rel) segment.
// Output: Mb [NK][128] bf16, k-swizzled per 32-channel tile for MFMA frags.
// ---------------------------------------------------------------------------
__global__ __launch_bounds__(256) void agg_k(const float* __restrict__ h,
                                             const float* __restrict__ xe,
                                             const int* __restrict__ ei,
                                             const int* __restrict__ perm,
                                             const int* __restrict__ offs,
                                             unsigned short* __restrict__ Mb, int NK) {
  int wv = threadIdx.x >> 6;
  int seg = blockIdx.x * 4 + wv;
  if (seg >= NK) return;
  int lane = threadIdx.x & 63;
  int half = lane >> 5, c = lane & 31;
  int start = offs[seg], end = offs[seg + 1];
  float4 acc = make_float4(0.f, 0.f, 0.f, 0.f);
  for (int i = start + half; i < end; i += 2) {
    int e = perm[i];
    int src = ei[e];
    float4 xv = ((const float4*)xe)[(size_t)e * 32 + c];
    float4 hv = ((const float4*)h)[(size_t)src * 32 + c];
    acc.x += fmaxf(xv.x + hv.x, 0.f);
    acc.y += fmaxf(xv.y + hv.y, 0.f);
    acc.z += fmaxf(xv.z + hv.z, 0.f);
    acc.w += fmaxf(xv.w + hv.w, 0.f);
  }
  acc.x += __shfl_xor(acc.x, 32);
  acc.y += __shfl_xor(acc.y, 32);
  acc.z += __shfl_xor(acc.z, 32);
  acc.w += __shfl_xor(acc.w, 32);
  if (half == 0) {
    int len = end - start;
    float inv = (len > 0) ? 1.0f / (float)len : 0.f;
    int pos = (c >> 3) * 32 + (c & 3) * 8 + ((c >> 2) & 1) * 4;
    ushort4 u;
    u.x = f2bf(acc.x * inv); u.y = f2bf(acc.y * inv);
    u.z = f2bf(acc.z * inv); u.w = f2bf(acc.w * inv);
    *(ushort4*)(Mb + (size_t)seg * 128 + pos) = u;
  }
}

// cast fp32 [N,128] -> bf16 swizzled [N,128]
__global__ __launch_bounds__(256) void cast_swz_k(const float* __restrict__ in,
                                                  unsigned short* __restrict__ outb, int n4) {
  int gi = blockIdx.x * 256 + threadIdx.x;
  if (gi >= n4) return;
  int n = gi >> 5, c = gi & 31;
  float4 v = ((const float4*)in)[gi];
  int pos = (c >> 3) * 32 + (c & 3) * 8 + ((c >> 2) & 1) * 4;
  ushort4 u;
  u.x = f2bf(v.x); u.y = f2bf(v.y); u.z = f2bf(v.z); u.w = f2bf(v.w);
  *(ushort4*)(outb + (size_t)n * 128 + pos) = u;
}

// W[1152,128] (weight_l | root_l) -> transposed [col][1152], k-swizzled, bf16
__global__ __launch_bounds__(256) void wcast_k(const float* __restrict__ W,
                                               const float* __restrict__ root,
                                               unsigned short* __restrict__ Whi) {
  int idx = blockIdx.x * 256 + threadIdx.x;   // 1152*128 = 147456
  if (idx >= 1152 * 128) return;
  int k = idx >> 7, col = idx & 127;
  float w = (k < 1024) ? W[idx] : root[idx - 1024 * 128];
  int kk = k & 31;
  int pos = (k & ~31) + ((kk & 15) >> 2) * 8 + (kk >> 4) * 4 + (kk & 3);
  Whi[col * 1152 + pos] = f2bf(w);
}

// ---------------------------------------------------------------------------
// MFMA GEMM: out[n,o] = sum_k A[n,k] * W[k,o] + bias[o]
// 256 thr = 4 waves. Wave wv: cols [wv*32, wv*32+32) (cf=2), rows r0..r0+63 (rf=4).
// A frags direct from global (L1-shared across waves); B frags from L2-resident W.
// No LDS in the main loop, no barriers -> deep pipelining.
// Fused BN column sum/sumsq epilogue.
// ---------------------------------------------------------------------------
__global__ __launch_bounds__(256) void gemm_k(
    const unsigned short* __restrict__ Mb,   // [N,1024] swz
    const unsigned short* __restrict__ hb,   // [N,128] swz
    const unsigned short* __restrict__ Whi,  // [128 cols][1152] swz-k
    const float* __restrict__ bias,
    float* __restrict__ out,
    float* __restrict__ colstats, int N) {
  __shared__ float ldsS[128], ldsQ[128];
  const int tid = threadIdx.x;
  const int wv = tid >> 6, lane = tid & 63;
  const int lr = lane & 15, g = lane >> 4;
  const int r0 = blockIdx.x * 64;
  const int cf0 = wv * 2;

  int row[4];
  #pragma unroll
  for (int rf = 0; rf < 4; ++rf) row[rf] = min(r0 + rf * 16 + lr, N - 1);

  const unsigned short* pb0 = Whi + (size_t)(cf0 * 16 + lr) * 1152 + g * 8;
  const unsigned short* pb1 = pb0 + 16 * 1152;

  f32x4 acc[4][2];
  #pragma unroll
  for (int a = 0; a < 4; ++a)
    #pragma unroll
    for (int b = 0; b < 2; ++b) acc[a][b] = (f32x4){0.f, 0.f, 0.f, 0.f};

  // K over Mb: 32 tiles of 32
  #pragma unroll 4
  for (int t = 0; t < 32; ++t) {
    bf16x8 b0 = *(const bf16x8*)(pb0 + t * 32);
    bf16x8 b1 = *(const bf16x8*)(pb1 + t * 32);
    #pragma unroll
    for (int rf = 0; rf < 4; ++rf) {
      bf16x8 a = *(const bf16x8*)(Mb + (size_t)row[rf] * 1024 + t * 32 + g * 8);
      acc[rf][0] = __builtin_amdgcn_mfma_f32_16x16x32_bf16(a, b0, acc[rf][0], 0, 0, 0);
      acc[rf][1] = __builtin_amdgcn_mfma_f32_16x16x32_bf16(a, b1, acc[rf][1], 0, 0, 0);
    }
  }
  // K over hb: 4 tiles of 32
  #pragma unroll
  for (int tt = 0; tt < 4; ++tt) {
    bf16x8 b0 = *(const bf16x8*)(pb0 + 1024 + tt * 32);
    bf16x8 b1 = *(const bf16x8*)(pb1 + 1024 + tt * 32);
    #pragma unroll
    for (int rf = 0; rf < 4; ++rf) {
      bf16x8 a = *(const bf16x8*)(hb + (size_t)row[rf] * 128 + tt * 32 + g * 8);
      acc[rf][0] = __builtin_amdgcn_mfma_f32_16x16x32_bf16(a, b0, acc[rf][0], 0, 0, 0);
      acc[rf][1] = __builtin_amdgcn_mfma_f32_16x16x32_bf16(a, b1, acc[rf][1], 0, 0, 0);
    }
  }

  // epilogue: bias, store, BN column stats
  #pragma unroll
  for (int c = 0; c < 2; ++c) {
    int col = (cf0 + c) * 16 + lr;
    float bs = bias[col];
    float s = 0.f, q = 0.f;
    #pragma unroll
    for (int rf = 0; rf < 4; ++rf) {
      #pragma unroll
      for (int j = 0; j < 4; ++j) {
        int r = r0 + rf * 16 + g * 4 + j;
        if (r < N) {
          float v = acc[rf][c][j] + bs;
          out[(size_t)r * 128 + col] = v;
          s += v; q += v * v;
        }
      }
    }
    s += __shfl_xor(s, 16); s += __shfl_xor(s, 32);
    q += __shfl_xor(q, 16); q += __shfl_xor(q, 32);
    if (g == 0) { ldsS[col] = s; ldsQ[col] = q; }
  }
  __syncthreads();
  if (tid < 128) {
    atomicAdd(&colstats[tid], ldsS[tid]);
    atomicAdd(&colstats[128 + tid], ldsQ[tid]);
  }
}

// ---------------------------------------------------------------------------
// BN apply; optionally also emit bf16-swizzled copy for next layer's root term
// ---------------------------------------------------------------------------
__global__ __launch_bounds__(256) void bn_apply_k(
    const float* __restrict__ in, float* __restrict__ out,
    unsigned short* __restrict__ hbOut,
    const float* __restrict__ colstats,
    const float* __restrict__ gamma, const float* __restrict__ beta,
    int N, int doRelu) {
  int gi = blockIdx.x * 256 + threadIdx.x;
  if (gi >= N * 32) return;
  int n = gi >> 5, c = gi & 31;
  int c0 = c * 4;
  float invN = 1.0f / (float)N;
  float4 v = ((const float4*)in)[gi];
  float4 o;
  #pragma unroll
  for (int j = 0; j < 4; ++j) {
    int cc = c0 + j;
    float mu = colstats[cc] * invN;
    float var = colstats[128 + cc] * invN - mu * mu;
    float scale = rsqrtf(var + BN_EPS) * gamma[cc];
    float shift = beta[cc] - mu * scale;
    float x = (j == 0) ? v.x : (j == 1) ? v.y : (j == 2) ? v.z : v.w;
    float y = x * scale + shift;
    if (doRelu) y = fmaxf(y, 0.f);
    if (j == 0) o.x = y; else if (j == 1) o.y = y; else if (j == 2) o.z = y; else o.w = y;
  }
  ((float4*)out)[gi] = o;
  if (hbOut) {
    int pos = (c >> 3) * 32 + (c & 3) * 8 + ((c >> 2) & 1) * 4;
    ushort4 u;
    u.x = f2bf(o.x); u.y = f2bf(o.y); u.z = f2bf(o.z); u.w = f2bf(o.w);
    *(ushort4*)(hbOut + (size_t)n * 128 + pos) = u;
  }
}

extern "C" void kernel_launch(void* const* d_in, const int* in_sizes, int n_in,
                              void* d_out, int out_size, void* d_ws, size_t ws_size,
                              hipStream_t stream) {
  const float* x      = (const float*)d_in[0];
  const float* xe     = (const float*)d_in[1];
  const int*   ei     = (const int*)d_in[2];
  const int*   et     = (const int*)d_in[3];
  const float* weight = (const float*)d_in[4];
  const float* root   = (const float*)d_in[5];
  const float* bias   = (const float*)d_in[6];
  const float* gamma  = (const float*)d_in[7];
  const float* beta   = (const float*)d_in[8];
  float* out = (float*)d_out;

  const int N = in_sizes[0] / D;   // 50000
  const int E = in_sizes[3];       // 500000
  const int NK = N * R;            // 400000

  // workspace layout (256B-aligned chunks)
  char* w = (char*)d_ws;
  size_t off = 0;
  auto alloc = [&](size_t bytes) { char* p = w + off; off = (off + bytes + 255) & ~(size_t)255; return p; };
  unsigned short* Mb   = (unsigned short*)alloc((size_t)NK * 128 * 2);
  unsigned short* hb   = (unsigned short*)alloc((size_t)N * 128 * 2);
  float*          h1   = (float*)alloc((size_t)N * 128 * 4);
  unsigned short* Whi  = (unsigned short*)alloc(1152 * 128 * 2);
  int*            offs = (int*)alloc((size_t)(NK + 1) * 4);
  int*            cnt  = (int*)alloc((size_t)NK * 4);
  int*            perm = (int*)alloc((size_t)E * 4);
  int*            bsum = (int*)alloc(512 * 4);
  float*          cst  = (float*)alloc(256 * 4);

  const int NB = (NK + 4095) / 4096;

  // --- counting sort (edge structure; shared by both layers) ---
  hipMemsetAsync(cnt, 0, (size_t)NK * 4, stream);
  hist_k<<<(E + 255) / 256, 256, 0, stream>>>(ei, et, cnt, E);
  scan_partial_k<<<NB, 256, 0, stream>>>(cnt, offs, bsum, NK);
  scan_bsums_k<<<1, 64, 0, stream>>>(bsum, NB);
  scan_addback_k<<<(NK + 255) / 256, 256, 0, stream>>>(offs, bsum, NK, E);
  hipMemsetAsync(cnt, 0, (size_t)NK * 4, stream);
  place_k<<<(E + 255) / 256, 256, 0, stream>>>(ei, et, offs, cnt, perm, E);

  const int aggBlocks  = (NK + 3) / 4;
  const int gemmBlocks = (N + 63) / 64;
  const int castBlocks = (N * 32 + 255) / 256;

  for (int l = 0; l < 2; ++l) {
    const float* hin = (l == 0) ? x : h1;
    float* opre      = (l == 0) ? h1 : out;

    wcast_k<<<576, 256, 0, stream>>>(weight + (size_t)l * 1024 * 128,
                                     root + (size_t)l * 128 * 128, Whi);
    agg_k<<<aggBlocks, 256, 0, stream>>>(hin, xe, ei, perm, offs, Mb, NK);
    if (l == 0)
      cast_swz_k<<<castBlocks, 256, 0, stream>>>(x, hb, N * 32);
    hipMemsetAsync(cst, 0, 256 * 4, stream);
    gemm_k<<<gemmBlocks, 256, 0, stream>>>(Mb, hb, Whi,
                                           bias + (size_t)l * D, opre, cst, N);
    bn_apply_k<<<castBlocks, 256, 0, stream>>>(
        opre, opre, (l == 0) ? hb : (unsigned short*)nullptr,
        cst, gamma + (size_t)l * D, beta + (size_t)l * D, N, (l == 0) ? 1 : 0);
  }
}

// Round 4
// 523.269 us; speedup vs baseline: 5.8454x; 1.2360x over previous
//
#include <hip/hip_runtime.h>
#include <hip/hip_bf16.h>

typedef __attribute__((ext_vector_type(8))) short bf16x8;
typedef __attribute__((ext_vector_type(4))) float f32x4;

constexpr int D = 128;
constexpr int R = 8;
constexpr float BN_EPS = 1e-5f;

__device__ __forceinline__ unsigned short f2bf(float x) {
  __hip_bfloat16 b = __float2bfloat16(x);
  union { __hip_bfloat16 b; unsigned short u; } c; c.b = b; return c.u;
}

// ---------------------------------------------------------------------------
// Counting sort of edges by key = dst*8 + rel (structure shared by both layers)
// ---------------------------------------------------------------------------
__global__ __launch_bounds__(256) void hist_k(const int* __restrict__ ei,
                                              const int* __restrict__ et,
                                              int* __restrict__ cnt, int E) {
  int e = blockIdx.x * 256 + threadIdx.x;
  if (e >= E) return;
  atomicAdd(&cnt[ei[E + e] * 8 + et[e]], 1);
}

__global__ __launch_bounds__(256) void scan_partial_k(const int* __restrict__ cnt,
                                                      int* __restrict__ offs,
                                                      int* __restrict__ bsum, int NK) {
  __shared__ int s[256];
  int tid = threadIdx.x;
  int base = blockIdx.x * 4096 + tid * 16;
  int loc[16];
  int sum = 0;
  #pragma unroll
  for (int i = 0; i < 16; ++i) {
    int idx = base + i;
    int v = (idx < NK) ? cnt[idx] : 0;
    loc[i] = sum; sum += v;
  }
  s[tid] = sum;
  __syncthreads();
  if (tid == 0) {
    int run = 0;
    for (int i = 0; i < 256; ++i) { int t = s[i]; s[i] = run; run += t; }
    bsum[blockIdx.x] = run;
  }
  __syncthreads();
  int off = s[tid];
  #pragma unroll
  for (int i = 0; i < 16; ++i) {
    int idx = base + i;
    if (idx < NK) offs[idx] = off + loc[i];
  }
}

__global__ void scan_bsums_k(int* __restrict__ bsum, int nb) {
  if (threadIdx.x == 0 && blockIdx.x == 0) {
    int run = 0;
    for (int b = 0; b < nb; ++b) { int t = bsum[b]; bsum[b] = run; run += t; }
  }
}

__global__ __launch_bounds__(256) void scan_addback_k(int* __restrict__ offs,
                                                      const int* __restrict__ bsum,
                                                      int NK, int E) {
  int idx = blockIdx.x * 256 + threadIdx.x;
  if (idx < NK) offs[idx] += bsum[idx >> 12];
  if (idx == 0) offs[NK] = E;
}

// place: also pre-gather src so agg has no dependent index chain
__global__ __launch_bounds__(256) void place_k(const int* __restrict__ ei,
                                               const int* __restrict__ et,
                                               const int* __restrict__ offs,
                                               int* __restrict__ cnt,
                                               int2* __restrict__ pairs, int E) {
  int e = blockIdx.x * 256 + threadIdx.x;
  if (e >= E) return;
  int key = ei[E + e] * 8 + et[e];
  int pos = offs[key] + atomicAdd(&cnt[key], 1);
  pairs[pos] = make_int2(e, ei[e]);
}

// ---------------------------------------------------------------------------
// Segment mean: one 32-lane group per (dst,rel) segment; 8 segments/block.
// Edge ids distributed in-register via shfl -> all gathers independent.
// Output: Mb [NK][128] bf16, k-swizzled per 32-channel tile for MFMA frags.
// ---------------------------------------------------------------------------
__global__ __launch_bounds__(256) void agg_k(const float* __restrict__ h,
                                             const float* __restrict__ xe,
                                             const int2* __restrict__ pairs,
                                             const int* __restrict__ offs,
                                             unsigned short* __restrict__ Mb, int NK) {
  int grp = threadIdx.x >> 5;
  int seg = blockIdx.x * 8 + grp;
  if (seg >= NK) return;
  int c = threadIdx.x & 31;
  int start = offs[seg], end = offs[seg + 1];
  int len = end - start;
  float4 acc = make_float4(0.f, 0.f, 0.f, 0.f);

#define EDGE_I(i) do { \
    int e_ = __shfl(pr.x, (i), 32); \
    int s_ = __shfl(pr.y, (i), 32); \
    float4 xv = ((const float4*)xe)[(size_t)e_ * 32 + c]; \
    float4 hv = ((const float4*)h)[(size_t)s_ * 32 + c]; \
    acc.x += fmaxf(xv.x + hv.x, 0.f); \
    acc.y += fmaxf(xv.y + hv.y, 0.f); \
    acc.z += fmaxf(xv.z + hv.z, 0.f); \
    acc.w += fmaxf(xv.w + hv.w, 0.f); \
  } while (0)

  for (int base = start; base < end; base += 32) {
    int m = min(32, end - base);
    int2 pr = pairs[base + min(c, m - 1)];
    EDGE_I(0);
    if (m >= 2) EDGE_I(1);
    if (m >= 3) EDGE_I(2);
    if (m >= 4) EDGE_I(3);
    for (int i = 4; i < m; ++i) EDGE_I(i);
  }
#undef EDGE_I

  float inv = (len > 0) ? 1.0f / (float)len : 0.f;
  int pos = (c >> 3) * 32 + (c & 3) * 8 + ((c >> 2) & 1) * 4;
  ushort4 u;
  u.x = f2bf(acc.x * inv); u.y = f2bf(acc.y * inv);
  u.z = f2bf(acc.z * inv); u.w = f2bf(acc.w * inv);
  *(ushort4*)(Mb + (size_t)seg * 128 + pos) = u;
}

// cast fp32 [N,128] -> bf16 swizzled [N,128]
__global__ __launch_bounds__(256) void cast_swz_k(const float* __restrict__ in,
                                                  unsigned short* __restrict__ outb, int n4) {
  int gi = blockIdx.x * 256 + threadIdx.x;
  if (gi >= n4) return;
  int n = gi >> 5, c = gi & 31;
  float4 v = ((const float4*)in)[gi];
  int pos = (c >> 3) * 32 + (c & 3) * 8 + ((c >> 2) & 1) * 4;
  ushort4 u;
  u.x = f2bf(v.x); u.y = f2bf(v.y); u.z = f2bf(v.z); u.w = f2bf(v.w);
  *(ushort4*)(outb + (size_t)n * 128 + pos) = u;
}

// W[1152,128] (weight_l | root_l) -> transposed [col][1152], k-swizzled, bf16
__global__ __launch_bounds__(256) void wcast_k(const float* __restrict__ W,
                                               const float* __restrict__ root,
                                               unsigned short* __restrict__ Whi) {
  int idx = blockIdx.x * 256 + threadIdx.x;   // 1152*128 = 147456
  if (idx >= 1152 * 128) return;
  int k = idx >> 7, col = idx & 127;
  float w = (k < 1024) ? W[idx] : root[idx - 1024 * 128];
  int kk = k & 31;
  int pos = (k & ~31) + ((kk & 15) >> 2) * 8 + (kk >> 4) * 4 + (kk & 3);
  Whi[col * 1152 + pos] = f2bf(w);
}

// ---------------------------------------------------------------------------
// MFMA GEMM: out[n,o] = sum_k A[n,k] * W[k,o] + bias[o]
// 256 thr = 4 waves. Block: 128 rows. Wave wv: cols [wv*32, wv*32+32), rf=8.
// A frags direct from global; B frags L1/L2-resident. No LDS in main loop.
// Fused BN column sum/sumsq epilogue.
// ---------------------------------------------------------------------------
__global__ __launch_bounds__(256) void gemm_k(
    const unsigned short* __restrict__ Mb,   // [N,1024] swz
    const unsigned short* __restrict__ hb,   // [N,128] swz
    const unsigned short* __restrict__ Whi,  // [128 cols][1152] swz-k
    const float* __restrict__ bias,
    float* __restrict__ out,
    float* __restrict__ colstats, int N) {
  __shared__ float ldsS[128], ldsQ[128];
  const int tid = threadIdx.x;
  const int wv = tid >> 6, lane = tid & 63;
  const int lr = lane & 15, g = lane >> 4;
  const int r0 = blockIdx.x * 128;
  const int cf0 = wv * 2;

  int row[8];
  #pragma unroll
  for (int rf = 0; rf < 8; ++rf) row[rf] = min(r0 + rf * 16 + lr, N - 1);

  const unsigned short* pb0 = Whi + (size_t)(cf0 * 16 + lr) * 1152 + g * 8;
  const unsigned short* pb1 = pb0 + 16 * 1152;

  f32x4 acc[8][2];
  #pragma unroll
  for (int a = 0; a < 8; ++a)
    #pragma unroll
    for (int b = 0; b < 2; ++b) acc[a][b] = (f32x4){0.f, 0.f, 0.f, 0.f};

  // K over Mb: 32 tiles of 32
  #pragma unroll 2
  for (int t = 0; t < 32; ++t) {
    bf16x8 b0 = *(const bf16x8*)(pb0 + t * 32);
    bf16x8 b1 = *(const bf16x8*)(pb1 + t * 32);
    #pragma unroll
    for (int rf = 0; rf < 8; ++rf) {
      bf16x8 a = *(const bf16x8*)(Mb + (size_t)row[rf] * 1024 + t * 32 + g * 8);
      acc[rf][0] = __builtin_amdgcn_mfma_f32_16x16x32_bf16(a, b0, acc[rf][0], 0, 0, 0);
      acc[rf][1] = __builtin_amdgcn_mfma_f32_16x16x32_bf16(a, b1, acc[rf][1], 0, 0, 0);
    }
  }
  // K over hb: 4 tiles of 32
  #pragma unroll
  for (int tt = 0; tt < 4; ++tt) {
    bf16x8 b0 = *(const bf16x8*)(pb0 + 1024 + tt * 32);
    bf16x8 b1 = *(const bf16x8*)(pb1 + 1024 + tt * 32);
    #pragma unroll
    for (int rf = 0; rf < 8; ++rf) {
      bf16x8 a = *(const bf16x8*)(hb + (size_t)row[rf] * 128 + tt * 32 + g * 8);
      acc[rf][0] = __builtin_amdgcn_mfma_f32_16x16x32_bf16(a, b0, acc[rf][0], 0, 0, 0);
      acc[rf][1] = __builtin_amdgcn_mfma_f32_16x16x32_bf16(a, b1, acc[rf][1], 0, 0, 0);
    }
  }

  // epilogue: bias, store, BN column stats
  #pragma unroll
  for (int c = 0; c < 2; ++c) {
    int col = (cf0 + c) * 16 + lr;
    float bs = bias[col];
    float s = 0.f, q = 0.f;
    #pragma unroll
    for (int rf = 0; rf < 8; ++rf) {
      #pragma unroll
      for (int j = 0; j < 4; ++j) {
        int r = r0 + rf * 16 + g * 4 + j;
        if (r < N) {
          float v = acc[rf][c][j] + bs;
          out[(size_t)r * 128 + col] = v;
          s += v; q += v * v;
        }
      }
    }
    s += __shfl_xor(s, 16); s += __shfl_xor(s, 32);
    q += __shfl_xor(q, 16); q += __shfl_xor(q, 32);
    if (g == 0) { ldsS[col] = s; ldsQ[col] = q; }
  }
  __syncthreads();
  if (tid < 128) {
    atomicAdd(&colstats[tid], ldsS[tid]);
    atomicAdd(&colstats[128 + tid], ldsQ[tid]);
  }
}

// ---------------------------------------------------------------------------
// BN apply; optionally also emit bf16-swizzled copy for next layer's root term
// ---------------------------------------------------------------------------
__global__ __launch_bounds__(256) void bn_apply_k(
    const float* __restrict__ in, float* __restrict__ out,
    unsigned short* __restrict__ hbOut,
    const float* __restrict__ colstats,
    const float* __restrict__ gamma, const float* __restrict__ beta,
    int N, int doRelu) {
  int gi = blockIdx.x * 256 + threadIdx.x;
  if (gi >= N * 32) return;
  int n = gi >> 5, c = gi & 31;
  int c0 = c * 4;
  float invN = 1.0f / (float)N;
  float4 v = ((const float4*)in)[gi];
  float4 o;
  #pragma unroll
  for (int j = 0; j < 4; ++j) {
    int cc = c0 + j;
    float mu = colstats[cc] * invN;
    float var = colstats[128 + cc] * invN - mu * mu;
    float scale = rsqrtf(var + BN_EPS) * gamma[cc];
    float shift = beta[cc] - mu * scale;
    float x = (j == 0) ? v.x : (j == 1) ? v.y : (j == 2) ? v.z : v.w;
    float y = x * scale + shift;
    if (doRelu) y = fmaxf(y, 0.f);
    if (j == 0) o.x = y; else if (j == 1) o.y = y; else if (j == 2) o.z = y; else o.w = y;
  }
  ((float4*)out)[gi] = o;
  if (hbOut) {
    int pos = (c >> 3) * 32 + (c & 3) * 8 + ((c >> 2) & 1) * 4;
    ushort4 u;
    u.x = f2bf(o.x); u.y = f2bf(o.y); u.z = f2bf(o.z); u.w = f2bf(o.w);
    *(ushort4*)(hbOut + (size_t)n * 128 + pos) = u;
  }
}

extern "C" void kernel_launch(void* const* d_in, const int* in_sizes, int n_in,
                              void* d_out, int out_size, void* d_ws, size_t ws_size,
                              hipStream_t stream) {
  const float* x      = (const float*)d_in[0];
  const float* xe     = (const float*)d_in[1];
  const int*   ei     = (const int*)d_in[2];
  const int*   et     = (const int*)d_in[3];
  const float* weight = (const float*)d_in[4];
  const float* root   = (const float*)d_in[5];
  const float* bias   = (const float*)d_in[6];
  const float* gamma  = (const float*)d_in[7];
  const float* beta   = (const float*)d_in[8];
  float* out = (float*)d_out;

  const int N = in_sizes[0] / D;   // 50000
  const int E = in_sizes[3];       // 500000
  const int NK = N * R;            // 400000

  // workspace layout (256B-aligned chunks)
  char* w = (char*)d_ws;
  size_t off = 0;
  auto alloc = [&](size_t bytes) { char* p = w + off; off = (off + bytes + 255) & ~(size_t)255; return p; };
  unsigned short* Mb   = (unsigned short*)alloc((size_t)NK * 128 * 2);
  unsigned short* hb   = (unsigned short*)alloc((size_t)N * 128 * 2);
  float*          h1   = (float*)alloc((size_t)N * 128 * 4);
  unsigned short* Whi  = (unsigned short*)alloc(1152 * 128 * 2);
  int*            offs = (int*)alloc((size_t)(NK + 1) * 4);
  int*            cnt  = (int*)alloc((size_t)NK * 4);
  int2*           pairs= (int2*)alloc((size_t)E * 8);
  int*            bsum = (int*)alloc(512 * 4);
  float*          cst  = (float*)alloc(256 * 4);

  const int NB = (NK + 4095) / 4096;

  // --- counting sort (edge structure; shared by both layers) ---
  hipMemsetAsync(cnt, 0, (size_t)NK * 4, stream);
  hist_k<<<(E + 255) / 256, 256, 0, stream>>>(ei, et, cnt, E);
  scan_partial_k<<<NB, 256, 0, stream>>>(cnt, offs, bsum, NK);
  scan_bsums_k<<<1, 64, 0, stream>>>(bsum, NB);
  scan_addback_k<<<(NK + 255) / 256, 256, 0, stream>>>(offs, bsum, NK, E);
  hipMemsetAsync(cnt, 0, (size_t)NK * 4, stream);
  place_k<<<(E + 255) / 256, 256, 0, stream>>>(ei, et, offs, cnt, pairs, E);

  const int aggBlocks  = (NK + 7) / 8;
  const int gemmBlocks = (N + 127) / 128;
  const int castBlocks = (N * 32 + 255) / 256;

  for (int l = 0; l < 2; ++l) {
    const float* hin = (l == 0) ? x : h1;
    float* opre      = (l == 0) ? h1 : out;

    wcast_k<<<576, 256, 0, stream>>>(weight + (size_t)l * 1024 * 128,
                                     root + (size_t)l * 128 * 128, Whi);
    agg_k<<<aggBlocks, 256, 0, stream>>>(hin, xe, pairs, offs, Mb, NK);
    if (l == 0)
      cast_swz_k<<<castBlocks, 256, 0, stream>>>(x, hb, N * 32);
    hipMemsetAsync(cst, 0, 256 * 4, stream);
    gemm_k<<<gemmBlocks, 256, 0, stream>>>(Mb, hb, Whi,
                                           bias + (size_t)l * D, opre, cst, N);
    bn_apply_k<<<castBlocks, 256, 0, stream>>>(
        opre, opre, (l == 0) ? hb : (unsigned short*)nullptr,
        cst, gamma + (size_t)l * D, beta + (size_t)l * D, N, (l == 0) ? 1 : 0);
  }
}

// Round 5
// 484.334 us; speedup vs baseline: 6.3153x; 1.0804x over previous
//
#include <hip/hip_runtime.h>
#include <hip/hip_bf16.h>

typedef __attribute__((ext_vector_type(8))) short bf16x8;
typedef __attribute__((ext_vector_type(4))) float f32x4;

constexpr int D = 128;
constexpr int R = 8;
constexpr float BN_EPS = 1e-5f;

__device__ __forceinline__ unsigned short f2bf(float x) {
  __hip_bfloat16 b = __float2bfloat16(x);
  union { __hip_bfloat16 b; unsigned short u; } c; c.b = b; return c.u;
}

// ---------------------------------------------------------------------------
// Counting sort of edges by key = dst*8 + rel (structure shared by both layers)
// ---------------------------------------------------------------------------
__global__ __launch_bounds__(256) void hist_k(const int* __restrict__ ei,
                                              const int* __restrict__ et,
                                              int* __restrict__ cnt, int E) {
  int e = blockIdx.x * 256 + threadIdx.x;
  if (e >= E) return;
  atomicAdd(&cnt[ei[E + e] * 8 + et[e]], 1);
}

__global__ __launch_bounds__(256) void scan_partial_k(const int* __restrict__ cnt,
                                                      int* __restrict__ offs,
                                                      int* __restrict__ bsum, int NK) {
  __shared__ int s[256];
  int tid = threadIdx.x;
  int base = blockIdx.x * 4096 + tid * 16;
  int loc[16];
  int sum = 0;
  #pragma unroll
  for (int i = 0; i < 16; ++i) {
    int idx = base + i;
    int v = (idx < NK) ? cnt[idx] : 0;
    loc[i] = sum; sum += v;
  }
  s[tid] = sum;
  __syncthreads();
  if (tid == 0) {
    int run = 0;
    for (int i = 0; i < 256; ++i) { int t = s[i]; s[i] = run; run += t; }
    bsum[blockIdx.x] = run;
  }
  __syncthreads();
  int off = s[tid];
  #pragma unroll
  for (int i = 0; i < 16; ++i) {
    int idx = base + i;
    if (idx < NK) offs[idx] = off + loc[i];
  }
}

__global__ void scan_bsums_k(int* __restrict__ bsum, int nb) {
  if (threadIdx.x == 0 && blockIdx.x == 0) {
    int run = 0;
    for (int b = 0; b < nb; ++b) { int t = bsum[b]; bsum[b] = run; run += t; }
  }
}

__global__ __launch_bounds__(256) void scan_addback_k(int* __restrict__ offs,
                                                      const int* __restrict__ bsum,
                                                      int NK, int E) {
  int idx = blockIdx.x * 256 + threadIdx.x;
  if (idx < NK) offs[idx] += bsum[idx >> 12];
  if (idx == 0) offs[NK] = E;
}

// place: also pre-gather src so agg has no dependent index chain
__global__ __launch_bounds__(256) void place_k(const int* __restrict__ ei,
                                               const int* __restrict__ et,
                                               const int* __restrict__ offs,
                                               int* __restrict__ cnt,
                                               int2* __restrict__ pairs, int E) {
  int e = blockIdx.x * 256 + threadIdx.x;
  if (e >= E) return;
  int key = ei[E + e] * 8 + et[e];
  int pos = offs[key] + atomicAdd(&cnt[key], 1);
  pairs[pos] = make_int2(e, ei[e]);
}

// ---------------------------------------------------------------------------
// Segment mean: each 32-lane group owns FOUR consecutive (dst,rel) segments
// (4x memory-level parallelism for the avg-len-1.25 case). Edge ids are
// distributed in-register via shfl -> all gathers independent.
// Output: Mb [NK][128] bf16, k-swizzled per 32-channel tile for MFMA frags.
// ---------------------------------------------------------------------------
__device__ __forceinline__ void edge_acc(float4& acc, int e, int s, int c,
                                         const float* __restrict__ h,
                                         const float* __restrict__ xe) {
  float4 xv = ((const float4*)xe)[(size_t)e * 32 + c];
  float4 hv = ((const float4*)h)[(size_t)s * 32 + c];
  acc.x += fmaxf(xv.x + hv.x, 0.f);
  acc.y += fmaxf(xv.y + hv.y, 0.f);
  acc.z += fmaxf(xv.z + hv.z, 0.f);
  acc.w += fmaxf(xv.w + hv.w, 0.f);
}

__global__ __launch_bounds__(256) void agg_k(const float* __restrict__ h,
                                             const float* __restrict__ xe,
                                             const int2* __restrict__ pairs,
                                             const int* __restrict__ offs,
                                             unsigned short* __restrict__ Mb, int NK) {
  int grp = threadIdx.x >> 5;
  int s0 = (blockIdx.x * 8 + grp) * 4;
  if (s0 >= NK) return;
  int c = threadIdx.x & 31;

  int4 ov = *(const int4*)(offs + s0);   // s0 % 4 == 0 -> 16B aligned
  int o4 = offs[s0 + 4];
  int st[4] = {ov.x, ov.y, ov.z, ov.w};
  int en[4] = {ov.y, ov.z, ov.w, o4};

  // issue all 4 pairs loads up front (independent)
  int2 pr[4];
  #pragma unroll
  for (int j = 0; j < 4; ++j) {
    int m = en[j] - st[j];
    if (m > 0) pr[j] = pairs[st[j] + min(c, min(m, 32) - 1)];
  }

  float4 acc[4];
  #pragma unroll
  for (int j = 0; j < 4; ++j) acc[j] = make_float4(0.f, 0.f, 0.f, 0.f);

  #pragma unroll
  for (int j = 0; j < 4; ++j) {
    int m = en[j] - st[j];
    if (m > 0) {
      int mm = min(m, 32);
      {
        int e0 = __shfl(pr[j].x, 0, 32), sB = __shfl(pr[j].y, 0, 32);
        edge_acc(acc[j], e0, sB, c, h, xe);
      }
      if (mm >= 2) { edge_acc(acc[j], __shfl(pr[j].x, 1, 32), __shfl(pr[j].y, 1, 32), c, h, xe); }
      if (mm >= 3) { edge_acc(acc[j], __shfl(pr[j].x, 2, 32), __shfl(pr[j].y, 2, 32), c, h, xe); }
      if (mm >= 4) { edge_acc(acc[j], __shfl(pr[j].x, 3, 32), __shfl(pr[j].y, 3, 32), c, h, xe); }
      for (int i = 4; i < mm; ++i)
        edge_acc(acc[j], __shfl(pr[j].x, i, 32), __shfl(pr[j].y, i, 32), c, h, xe);
      // rare: segments longer than 32
      for (int base = st[j] + 32; base < en[j]; base += 32) {
        int mm2 = min(32, en[j] - base);
        int2 pr2 = pairs[base + min(c, mm2 - 1)];
        for (int i = 0; i < mm2; ++i)
          edge_acc(acc[j], __shfl(pr2.x, i, 32), __shfl(pr2.y, i, 32), c, h, xe);
      }
    }
  }

  int pos = (c >> 3) * 32 + (c & 3) * 8 + ((c >> 2) & 1) * 4;
  #pragma unroll
  for (int j = 0; j < 4; ++j) {
    int len = en[j] - st[j];
    float inv = (len > 0) ? 1.0f / (float)len : 0.f;
    ushort4 u;
    u.x = f2bf(acc[j].x * inv); u.y = f2bf(acc[j].y * inv);
    u.z = f2bf(acc[j].z * inv); u.w = f2bf(acc[j].w * inv);
    *(ushort4*)(Mb + (size_t)(s0 + j) * 128 + pos) = u;
  }
}

// cast fp32 [N,128] -> bf16 swizzled [N,128]
__global__ __launch_bounds__(256) void cast_swz_k(const float* __restrict__ in,
                                                  unsigned short* __restrict__ outb, int n4) {
  int gi = blockIdx.x * 256 + threadIdx.x;
  if (gi >= n4) return;
  int n = gi >> 5, c = gi & 31;
  float4 v = ((const float4*)in)[gi];
  int pos = (c >> 3) * 32 + (c & 3) * 8 + ((c >> 2) & 1) * 4;
  ushort4 u;
  u.x = f2bf(v.x); u.y = f2bf(v.y); u.z = f2bf(v.z); u.w = f2bf(v.w);
  *(ushort4*)(outb + (size_t)n * 128 + pos) = u;
}

// W[1152,128] (weight_l | root_l) -> transposed [col][1152], k-swizzled, bf16
__global__ __launch_bounds__(256) void wcast_k(const float* __restrict__ W,
                                               const float* __restrict__ root,
                                               unsigned short* __restrict__ Whi) {
  int idx = blockIdx.x * 256 + threadIdx.x;   // 1152*128 = 147456
  if (idx >= 1152 * 128) return;
  int k = idx >> 7, col = idx & 127;
  float w = (k < 1024) ? W[idx] : root[idx - 1024 * 128];
  int kk = k & 31;
  int pos = (k & ~31) + ((kk & 15) >> 2) * 8 + (kk >> 4) * 4 + (kk & 3);
  Whi[col * 1152 + pos] = f2bf(w);
}

// ---------------------------------------------------------------------------
// MFMA GEMM: out[n,o] = sum_k A[n,k] * W[k,o] + bias[o]
// 256 thr = 4 waves. Block: 128 rows. Wave wv: cols [wv*32, wv*32+32), rf=8.
// A frags direct from global; B frags L1/L2-resident. No LDS in main loop.
// Fused BN column sum/sumsq epilogue.
// ---------------------------------------------------------------------------
__global__ __launch_bounds__(256) void gemm_k(
    const unsigned short* __restrict__ Mb,   // [N,1024] swz
    const unsigned short* __restrict__ hb,   // [N,128] swz
    const unsigned short* __restrict__ Whi,  // [128 cols][1152] swz-k
    const float* __restrict__ bias,
    float* __restrict__ out,
    float* __restrict__ colstats, int N) {
  __shared__ float ldsS[128], ldsQ[128];
  const int tid = threadIdx.x;
  const int wv = tid >> 6, lane = tid & 63;
  const int lr = lane & 15, g = lane >> 4;
  const int r0 = blockIdx.x * 128;
  const int cf0 = wv * 2;

  int row[8];
  #pragma unroll
  for (int rf = 0; rf < 8; ++rf) row[rf] = min(r0 + rf * 16 + lr, N - 1);

  const unsigned short* pb0 = Whi + (size_t)(cf0 * 16 + lr) * 1152 + g * 8;
  const unsigned short* pb1 = pb0 + 16 * 1152;

  f32x4 acc[8][2];
  #pragma unroll
  for (int a = 0; a < 8; ++a)
    #pragma unroll
    for (int b = 0; b < 2; ++b) acc[a][b] = (f32x4){0.f, 0.f, 0.f, 0.f};

  // K over Mb: 32 tiles of 32
  #pragma unroll 2
  for (int t = 0; t < 32; ++t) {
    bf16x8 b0 = *(const bf16x8*)(pb0 + t * 32);
    bf16x8 b1 = *(const bf16x8*)(pb1 + t * 32);
    #pragma unroll
    for (int rf = 0; rf < 8; ++rf) {
      bf16x8 a = *(const bf16x8*)(Mb + (size_t)row[rf] * 1024 + t * 32 + g * 8);
      acc[rf][0] = __builtin_amdgcn_mfma_f32_16x16x32_bf16(a, b0, acc[rf][0], 0, 0, 0);
      acc[rf][1] = __builtin_amdgcn_mfma_f32_16x16x32_bf16(a, b1, acc[rf][1], 0, 0, 0);
    }
  }
  // K over hb: 4 tiles of 32
  #pragma unroll
  for (int tt = 0; tt < 4; ++tt) {
    bf16x8 b0 = *(const bf16x8*)(pb0 + 1024 + tt * 32);
    bf16x8 b1 = *(const bf16x8*)(pb1 + 1024 + tt * 32);
    #pragma unroll
    for (int rf = 0; rf < 8; ++rf) {
      bf16x8 a = *(const bf16x8*)(hb + (size_t)row[rf] * 128 + tt * 32 + g * 8);
      acc[rf][0] = __builtin_amdgcn_mfma_f32_16x16x32_bf16(a, b0, acc[rf][0], 0, 0, 0);
      acc[rf][1] = __builtin_amdgcn_mfma_f32_16x16x32_bf16(a, b1, acc[rf][1], 0, 0, 0);
    }
  }

  // epilogue: bias, store, BN column stats
  #pragma unroll
  for (int c = 0; c < 2; ++c) {
    int col = (cf0 + c) * 16 + lr;
    float bs = bias[col];
    float s = 0.f, q = 0.f;
    #pragma unroll
    for (int rf = 0; rf < 8; ++rf) {
      #pragma unroll
      for (int j = 0; j < 4; ++j) {
        int r = r0 + rf * 16 + g * 4 + j;
        if (r < N) {
          float v = acc[rf][c][j] + bs;
          out[(size_t)r * 128 + col] = v;
          s += v; q += v * v;
        }
      }
    }
    s += __shfl_xor(s, 16); s += __shfl_xor(s, 32);
    q += __shfl_xor(q, 16); q += __shfl_xor(q, 32);
    if (g == 0) { ldsS[col] = s; ldsQ[col] = q; }
  }
  __syncthreads();
  if (tid < 128) {
    atomicAdd(&colstats[tid], ldsS[tid]);
    atomicAdd(&colstats[128 + tid], ldsQ[tid]);
  }
}

// ---------------------------------------------------------------------------
// BN apply; optionally also emit bf16-swizzled copy for next layer's root term
// ---------------------------------------------------------------------------
__global__ __launch_bounds__(256) void bn_apply_k(
    const float* __restrict__ in, float* __restrict__ out,
    unsigned short* __restrict__ hbOut,
    const float* __restrict__ colstats,
    const float* __restrict__ gamma, const float* __restrict__ beta,
    int N, int doRelu) {
  int gi = blockIdx.x * 256 + threadIdx.x;
  if (gi >= N * 32) return;
  int n = gi >> 5, c = gi & 31;
  int c0 = c * 4;
  float invN = 1.0f / (float)N;
  float4 v = ((const float4*)in)[gi];
  float4 o;
  #pragma unroll
  for (int j = 0; j < 4; ++j) {
    int cc = c0 + j;
    float mu = colstats[cc] * invN;
    float var = colstats[128 + cc] * invN - mu * mu;
    float scale = rsqrtf(var + BN_EPS) * gamma[cc];
    float shift = beta[cc] - mu * scale;
    float x = (j == 0) ? v.x : (j == 1) ? v.y : (j == 2) ? v.z : v.w;
    float y = x * scale + shift;
    if (doRelu) y = fmaxf(y, 0.f);
    if (j == 0) o.x = y; else if (j == 1) o.y = y; else if (j == 2) o.z = y; else o.w = y;
  }
  ((float4*)out)[gi] = o;
  if (hbOut) {
    int pos = (c >> 3) * 32 + (c & 3) * 8 + ((c >> 2) & 1) * 4;
    ushort4 u;
    u.x = f2bf(o.x); u.y = f2bf(o.y); u.z = f2bf(o.z); u.w = f2bf(o.w);
    *(ushort4*)(hbOut + (size_t)n * 128 + pos) = u;
  }
}

extern "C" void kernel_launch(void* const* d_in, const int* in_sizes, int n_in,
                              void* d_out, int out_size, void* d_ws, size_t ws_size,
                              hipStream_t stream) {
  const float* x      = (const float*)d_in[0];
  const float* xe     = (const float*)d_in[1];
  const int*   ei     = (const int*)d_in[2];
  const int*   et     = (const int*)d_in[3];
  const float* weight = (const float*)d_in[4];
  const float* root   = (const float*)d_in[5];
  const float* bias   = (const float*)d_in[6];
  const float* gamma  = (const float*)d_in[7];
  const float* beta   = (const float*)d_in[8];
  float* out = (float*)d_out;

  const int N = in_sizes[0] / D;   // 50000
  const int E = in_sizes[3];       // 500000
  const int NK = N * R;            // 400000

  // workspace layout (256B-aligned chunks)
  char* w = (char*)d_ws;
  size_t off = 0;
  auto alloc = [&](size_t bytes) { char* p = w + off; off = (off + bytes + 255) & ~(size_t)255; return p; };
  unsigned short* Mb   = (unsigned short*)alloc((size_t)NK * 128 * 2);
  unsigned short* hb   = (unsigned short*)alloc((size_t)N * 128 * 2);
  float*          h1   = (float*)alloc((size_t)N * 128 * 4);
  unsigned short* Whi  = (unsigned short*)alloc(1152 * 128 * 2);
  int*            offs = (int*)alloc((size_t)(NK + 1) * 4);
  int*            cnt  = (int*)alloc((size_t)NK * 4);
  int2*           pairs= (int2*)alloc((size_t)E * 8);
  int*            bsum = (int*)alloc(512 * 4);
  float*          cst  = (float*)alloc(256 * 4);

  const int NB = (NK + 4095) / 4096;

  // --- counting sort (edge structure; shared by both layers) ---
  hipMemsetAsync(cnt, 0, (size_t)NK * 4, stream);
  hist_k<<<(E + 255) / 256, 256, 0, stream>>>(ei, et, cnt, E);
  scan_partial_k<<<NB, 256, 0, stream>>>(cnt, offs, bsum, NK);
  scan_bsums_k<<<1, 64, 0, stream>>>(bsum, NB);
  scan_addback_k<<<(NK + 255) / 256, 256, 0, stream>>>(offs, bsum, NK, E);
  hipMemsetAsync(cnt, 0, (size_t)NK * 4, stream);
  place_k<<<(E + 255) / 256, 256, 0, stream>>>(ei, et, offs, cnt, pairs, E);

  const int aggBlocks  = (NK + 31) / 32;
  const int gemmBlocks = (N + 127) / 128;
  const int castBlocks = (N * 32 + 255) / 256;

  for (int l = 0; l < 2; ++l) {
    const float* hin = (l == 0) ? x : h1;
    float* opre      = (l == 0) ? h1 : out;

    wcast_k<<<576, 256, 0, stream>>>(weight + (size_t)l * 1024 * 128,
                                     root + (size_t)l * 128 * 128, Whi);
    agg_k<<<aggBlocks, 256, 0, stream>>>(hin, xe, pairs, offs, Mb, NK);
    if (l == 0)
      cast_swz_k<<<castBlocks, 256, 0, stream>>>(x, hb, N * 32);
    hipMemsetAsync(cst, 0, 256 * 4, stream);
    gemm_k<<<gemmBlocks, 256, 0, stream>>>(Mb, hb, Whi,
                                           bias + (size_t)l * D, opre, cst, N);
    bn_apply_k<<<castBlocks, 256, 0, stream>>>(
        opre, opre, (l == 0) ? hb : (unsigned short*)nullptr,
        cst, gamma + (size_t)l * D, beta + (size_t)l * D, N, (l == 0) ? 1 : 0);
  }
}